// Round 1
// baseline (54.725 us; speedup 1.0000x reference)
//
#include <hip/hip_runtime.h>
#include <math.h>

#define TAU_INV 50.0f   // 1 / 0.02

__device__ __forceinline__ void osm_merge(float& m, float& s, float& sx, float& sy,
                                          float m2, float s2, float sx2, float sy2) {
    float nm = fmaxf(m, m2);
    float c1 = __expf(m - nm);
    float c2 = __expf(m2 - nm);
    s  = s  * c1 + s2  * c2;
    sx = sx * c1 + sx2 * c2;
    sy = sy * c1 + sy2 * c2;
    m = nm;
}

// One block (256 threads) per (b,n) row of length HW.
__global__ __launch_bounds__(256) void soft_argmax_rows(
        const float* __restrict__ logits,
        const float* __restrict__ gt_xy,
        const int* __restrict__ HimgP,
        const int* __restrict__ WimgP,
        float* __restrict__ row_err,
        int W, int H) {
    const int row = blockIdx.x;
    const int HW  = W * H;
    const int tid = threadIdx.x;
    const float4* b4 = (const float4*)(logits + (size_t)row * (size_t)HW);
    const int nvec = HW >> 2;

    float m = -INFINITY, s = 0.f, sx = 0.f, sy = 0.f;

    for (int i = tid; i < nvec; i += 256) {
        float4 v = b4[i];
        int l0 = i << 2;
        int y  = l0 / W;            // W is a multiple of 4 -> y constant over the 4 elems
        int x0 = l0 - y * W;
        float fy = (float)y;
        float vv[4] = {v.x, v.y, v.z, v.w};
        #pragma unroll
        for (int j = 0; j < 4; ++j) {
            float a  = vv[j] * TAU_INV;
            float fx = (float)(x0 + j);
            if (a <= m) {
                float w = __expf(a - m);
                s  += w;
                sx += w * fx;
                sy += w * fy;
            } else {
                float c = __expf(m - a);
                s  = s  * c + 1.f;
                sx = sx * c + fx;
                sy = sy * c + fy;
                m = a;
            }
        }
    }

    // wave (64-lane) butterfly reduction
    #pragma unroll
    for (int off = 32; off >= 1; off >>= 1) {
        float m2  = __shfl_xor(m,  off);
        float s2  = __shfl_xor(s,  off);
        float sx2 = __shfl_xor(sx, off);
        float sy2 = __shfl_xor(sy, off);
        osm_merge(m, s, sx, sy, m2, s2, sx2, sy2);
    }

    __shared__ float sm[4], ss[4], ssx[4], ssy[4];
    const int wave = tid >> 6, lane = tid & 63;
    if (lane == 0) { sm[wave] = m; ss[wave] = s; ssx[wave] = sx; ssy[wave] = sy; }
    __syncthreads();

    if (tid == 0) {
        #pragma unroll
        for (int wv = 1; wv < 4; ++wv)
            osm_merge(m, s, sx, sy, sm[wv], ss[wv], ssx[wv], ssy[wv]);
        float px = sx / s;
        float py = sy / s;
        float Wimg = (float)WimgP[0];
        float Himg = (float)HimgP[0];
        float gxf = gt_xy[2 * row + 0] * ((float)(W - 1) / (Wimg - 1.f));
        float gyf = gt_xy[2 * row + 1] * ((float)(H - 1) / (Himg - 1.f));
        float dx = 2.f * (px - gxf) / (float)(W - 1);
        float dy = 2.f * (py - gyf) / (float)(H - 1);
        row_err[row] = sqrtf(dx * dx + dy * dy);
    }
}

// Deterministic single-block sum of n floats -> out[0]
__global__ __launch_bounds__(256) void sum_rows(const float* __restrict__ row_err,
                                                float* __restrict__ out, int n) {
    const int tid = threadIdx.x;
    float acc = 0.f;
    for (int i = tid; i < n; i += 256) acc += row_err[i];
    #pragma unroll
    for (int off = 32; off >= 1; off >>= 1) acc += __shfl_xor(acc, off);
    __shared__ float sw[4];
    const int wave = tid >> 6, lane = tid & 63;
    if (lane == 0) sw[wave] = acc;
    __syncthreads();
    if (tid == 0) out[0] = sw[0] + sw[1] + sw[2] + sw[3];
}

extern "C" void kernel_launch(void* const* d_in, const int* in_sizes, int n_in,
                              void* d_out, int out_size, void* d_ws, size_t ws_size,
                              hipStream_t stream) {
    const float* logits = (const float*)d_in[0];
    const float* gt_xy  = (const float*)d_in[1];
    // d_in[2] = grid (unused: coords derived from index)
    const int*   HimgP  = (const int*)d_in[3];
    const int*   WimgP  = (const int*)d_in[4];

    const int HW = in_sizes[2] / 2;       // grid has HW rows of (x, y)
    const int BN = in_sizes[1] / 2;       // gt_xy has BN rows of (x, y)
    // feature map is square: W = H = sqrt(HW)
    int W = 1;
    while (W * W < HW) W <<= 1;
    if (W * W != HW) W = (int)(sqrtf((float)HW) + 0.5f);
    const int H = HW / W;

    float* row_err = (float*)d_ws;        // BN floats
    float* out     = (float*)d_out;

    soft_argmax_rows<<<BN, 256, 0, stream>>>(logits, gt_xy, HimgP, WimgP, row_err, W, H);
    sum_rows<<<1, 256, 0, stream>>>(row_err, out, BN);
}

// Round 2
// 51.904 us; speedup vs baseline: 1.0544x; 1.0544x over previous
//
#include <hip/hip_runtime.h>
#include <math.h>

#define TAU_INV 50.0f   // 1 / 0.02

__device__ __forceinline__ void osm_merge(float& m, float& s, float& sx, float& sy,
                                          float m2, float s2, float sx2, float sy2) {
    float nm = fmaxf(m, m2);
    float c1 = __expf(m - nm);
    float c2 = __expf(m2 - nm);
    s  = s  * c1 + s2  * c2;
    sx = sx * c1 + sx2 * c2;
    sy = sy * c1 + sy2 * c2;
    m  = nm;
}

// branchless online-softmax accumulate of one element (logit already scaled)
__device__ __forceinline__ void osm_elem(float& m, float& s, float& sx, float& sy,
                                         float a, float fx, float fy) {
    float nm = fmaxf(m, a);
    float c  = __expf(m - nm);
    float w  = __expf(a - nm);
    s  = fmaf(s,  c, w);
    sx = fmaf(sx, c, w * fx);
    sy = fmaf(sy, c, w * fy);
    m  = nm;
}

// 2 blocks per row; each block reduces elems_per_blk contiguous logits into an
// online-softmax partial (m, s, sx, sy) written to part[blockIdx.x].
__global__ __launch_bounds__(256) void soft_argmax_part(
        const float* __restrict__ logits,
        float4* __restrict__ part,
        int W, int elems_per_blk, float invW) {
    const int blk = blockIdx.x;
    const int tid = threadIdx.x;
    const int nvec = elems_per_blk >> 2;
    const float4* b4 = (const float4*)logits + (size_t)blk * (size_t)nvec;
    const int base_l = (blk & 1) * elems_per_blk;   // element offset within the row

    float m = -INFINITY, s = 0.f, sx = 0.f, sy = 0.f;

    for (int i = tid; i < nvec; i += 512) {
        // issue both loads before any compute
        const int i1 = i + 256;
        float4 v0 = b4[i];
        float4 v1;
        bool have1 = (i1 < nvec);
        if (have1) v1 = b4[i1];

        {
            int l0 = base_l + (i << 2);
            int y0 = (int)((float)l0 * invW);
            if (y0 * W > l0) --y0;
            else if ((y0 + 1) * W <= l0) ++y0;
            int x0 = l0 - y0 * W;               // W %4==0 -> y const over the 4 elems
            float fy = (float)y0;
            osm_elem(m, s, sx, sy, v0.x * TAU_INV, (float)(x0 + 0), fy);
            osm_elem(m, s, sx, sy, v0.y * TAU_INV, (float)(x0 + 1), fy);
            osm_elem(m, s, sx, sy, v0.z * TAU_INV, (float)(x0 + 2), fy);
            osm_elem(m, s, sx, sy, v0.w * TAU_INV, (float)(x0 + 3), fy);
        }
        if (have1) {
            int l0 = base_l + (i1 << 2);
            int y0 = (int)((float)l0 * invW);
            if (y0 * W > l0) --y0;
            else if ((y0 + 1) * W <= l0) ++y0;
            int x0 = l0 - y0 * W;
            float fy = (float)y0;
            osm_elem(m, s, sx, sy, v1.x * TAU_INV, (float)(x0 + 0), fy);
            osm_elem(m, s, sx, sy, v1.y * TAU_INV, (float)(x0 + 1), fy);
            osm_elem(m, s, sx, sy, v1.z * TAU_INV, (float)(x0 + 2), fy);
            osm_elem(m, s, sx, sy, v1.w * TAU_INV, (float)(x0 + 3), fy);
        }
    }

    // 64-lane butterfly reduction
    #pragma unroll
    for (int off = 32; off >= 1; off >>= 1) {
        float m2  = __shfl_xor(m,  off);
        float s2  = __shfl_xor(s,  off);
        float sx2 = __shfl_xor(sx, off);
        float sy2 = __shfl_xor(sy, off);
        osm_merge(m, s, sx, sy, m2, s2, sx2, sy2);
    }

    __shared__ float sm[4], ss[4], ssx[4], ssy[4];
    const int wave = tid >> 6, lane = tid & 63;
    if (lane == 0) { sm[wave] = m; ss[wave] = s; ssx[wave] = sx; ssy[wave] = sy; }
    __syncthreads();

    if (tid == 0) {
        #pragma unroll
        for (int wv = 1; wv < 4; ++wv)
            osm_merge(m, s, sx, sy, sm[wv], ss[wv], ssx[wv], ssy[wv]);
        part[blk] = make_float4(m, s, sx, sy);
    }
}

// Merge the 2 partials per row, compute per-row error, sum all rows -> out[0].
__global__ __launch_bounds__(256) void finish(
        const float4* __restrict__ part,
        const float* __restrict__ gt_xy,
        const int* __restrict__ HimgP,
        const int* __restrict__ WimgP,
        float* __restrict__ out,
        int W, int H, int BN) {
    const int tid = threadIdx.x;
    const float Wimg = (float)WimgP[0];
    const float Himg = (float)HimgP[0];
    const float sxin = (float)(W - 1) / (Wimg - 1.f);
    const float syin = (float)(H - 1) / (Himg - 1.f);
    const float nx = 2.f / (float)(W - 1);
    const float ny = 2.f / (float)(H - 1);

    float acc = 0.f;
    for (int r = tid; r < BN; r += 256) {
        float4 p0 = part[2 * r + 0];
        float4 p1 = part[2 * r + 1];
        float m = p0.x, s = p0.y, sx = p0.z, sy = p0.w;
        osm_merge(m, s, sx, sy, p1.x, p1.y, p1.z, p1.w);
        float px = sx / s;
        float py = sy / s;
        float gx = gt_xy[2 * r + 0] * sxin;
        float gy = gt_xy[2 * r + 1] * syin;
        float dx = (px - gx) * nx;
        float dy = (py - gy) * ny;
        acc += sqrtf(dx * dx + dy * dy);
    }
    #pragma unroll
    for (int off = 32; off >= 1; off >>= 1) acc += __shfl_xor(acc, off);
    __shared__ float sw[4];
    const int wave = tid >> 6, lane = tid & 63;
    if (lane == 0) sw[wave] = acc;
    __syncthreads();
    if (tid == 0) out[0] = sw[0] + sw[1] + sw[2] + sw[3];
}

extern "C" void kernel_launch(void* const* d_in, const int* in_sizes, int n_in,
                              void* d_out, int out_size, void* d_ws, size_t ws_size,
                              hipStream_t stream) {
    const float* logits = (const float*)d_in[0];
    const float* gt_xy  = (const float*)d_in[1];
    // d_in[2] = grid (unused: coords derived from index)
    const int*   HimgP  = (const int*)d_in[3];
    const int*   WimgP  = (const int*)d_in[4];

    const int HW = in_sizes[2] / 2;       // grid has HW rows of (x, y)
    const int BN = in_sizes[1] / 2;       // gt_xy has BN rows of (x, y)
    int W = 1;
    while (W * W < HW) W <<= 1;
    if (W * W != HW) W = (int)(sqrtf((float)HW) + 0.5f);
    const int H = HW / W;

    float4* part = (float4*)d_ws;         // 2*BN float4 partials
    float*  out  = (float*)d_out;

    const int elems_per_blk = HW / 2;
    soft_argmax_part<<<2 * BN, 256, 0, stream>>>(logits, part, W, elems_per_blk,
                                                 1.0f / (float)W);
    finish<<<1, 256, 0, stream>>>(part, gt_xy, HimgP, WimgP, out, W, H, BN);
}